// Round 2
// baseline (194.593 us; speedup 1.0000x reference)
//
#include <hip/hip_runtime.h>

// CASREL loss. B=32,S=512,H=1024,R=64 -> scalar fp32 loss.
// R2: barrier-free streaming MFMA GEMM. Each wave: 16 rows x 80 cols,
// A (fp32->bf16 in regs) + B (bf16, L2-resident) loaded global->reg with
// register double-buffer; no LDS staging at all. subject@Wo folded into
// per-batch rowBias by a fused prep kernel.

#define B_  32
#define S_  512
#define H_  1024
#define R_  64
#define M_  (B_ * S_)      // 16384 rows
#define NPAD 160           // 130 valid cols padded to 10*16
#define NVALID 130

typedef __attribute__((ext_vector_type(4))) float  floatx4;
typedef __attribute__((ext_vector_type(8))) short  short8;     // 8 bf16

__device__ __forceinline__ unsigned short f2bf(float f) {
    unsigned int u = __float_as_uint(f);
    u = (u + 0x7FFFu + ((u >> 16) & 1u)) >> 16;   // RNE
    return (unsigned short)u;
}

// ---- K1 (fused): blocks 0..159 transpose/pad weights to WtG[160][1024] bf16;
//      blocks 160..191 compute per-batch rowBias[b][160] = bias + subj@Wo ----
__global__ __launch_bounds__(256) void prep_kernel(
        const float* __restrict__ ctx,  const float* __restrict__ head,
        const float* __restrict__ tail,
        const float* __restrict__ Ws_h, const float* __restrict__ Ws_t,
        const float* __restrict__ Wo_h, const float* __restrict__ Wo_t,
        const float* __restrict__ bo_h, const float* __restrict__ bo_t,
        const float* __restrict__ bs_h, const float* __restrict__ bs_t,
        unsigned short* __restrict__ WtG, float* __restrict__ rowBias) {
    const int blk = blockIdx.x, tid = threadIdx.x;
    if (blk < NPAD) {
        // transpose column blk of [Wo_h | Wo_t | Ws_h | Ws_t | 0] into WtG row
        const int n = blk;
        for (int k = tid; k < H_; k += 256) {
            float v;
            if (n < 64)        v = Wo_h[k * R_ + n];
            else if (n < 128)  v = Wo_t[k * R_ + (n - 64)];
            else if (n == 128) v = Ws_h[k];
            else if (n == 129) v = Ws_t[k];
            else               v = 0.0f;
            WtG[n * H_ + k] = f2bf(v);
        }
        return;
    }
    // ---- subject path, b = blk - 160 ----
    const int b = blk - NPAD;
    __shared__ float subj[H_];
    __shared__ float part[256];
    __shared__ int cnt;
    __shared__ int   sidx[4];
    __shared__ float sw[4];
    if (tid == 0) cnt = 0;
    __syncthreads();
    for (int s = tid; s < S_; s += 256) {
        float w = 0.5f * (head[b * S_ + s] + tail[b * S_ + s]);
        if (w != 0.0f) {
            int i = atomicAdd(&cnt, 1);
            if (i < 4) { sidx[i] = s; sw[i] = w; }
        }
    }
    __syncthreads();
    const int nnz = cnt < 4 ? cnt : 4;
    for (int h = tid; h < H_; h += 256) {
        float a = 0.0f;
        for (int i = 0; i < nnz; i++)
            a += sw[i] * ctx[((size_t)b * S_ + sidx[i]) * H_ + h];
        subj[h] = a;
    }
    __syncthreads();
    // GEMV subj[1024] @ W[1024][128]: tid = hf*128 + c, coalesced W reads
    {
        const int c = tid & 127, hf = tid >> 7;
        const float* W = (c < 64) ? (Wo_h + c) : (Wo_t + (c - 64));
        float a = 0.0f;
        const int k0 = hf * 512;
#pragma unroll 8
        for (int k = k0; k < k0 + 512; k++)
            a += subj[k] * W[(size_t)k * R_];
        part[tid] = a;
    }
    __syncthreads();
    if (tid < NPAD) {
        float v;
        if (tid < 128)
            v = part[tid] + part[128 + tid] + (tid < 64 ? bo_h[tid] : bo_t[tid - 64]);
        else if (tid == 128) v = bs_h[0];
        else if (tid == 129) v = bs_t[0];
        else                 v = 0.0f;
        rowBias[b * NPAD + tid] = v;
    }
}

// ---- K2: barrier-free fused GEMM + BCE + masked reduction ----
__global__ __launch_bounds__(256) void main_kernel(
        const float* __restrict__ ctx, const unsigned short* __restrict__ WtG,
        const float* __restrict__ rowBias, const float* __restrict__ masks,
        const float* __restrict__ ash, const float* __restrict__ ast,
        const float* __restrict__ oh, const float* __restrict__ ot,
        float* __restrict__ accum) {
    __shared__ float rbuf[4];
    const int tid  = threadIdx.x;
    const int gm0  = blockIdx.x * 32;       // 32 rows per block
    const int b    = gm0 >> 9;
    const int wave = tid >> 6, lane = tid & 63;
    const int wm = wave & 1;                // row half  (16 rows)
    const int wn = wave >> 1;               // col half  (80 cols = 5 tiles)
    const int lr = lane & 15, q = lane >> 4;

    // per-block mask sum (rows gm0..gm0+31)
    if (tid < 32) {
        float mv = masks[gm0 + tid];
#pragma unroll
        for (int o = 16; o > 0; o >>= 1) mv += __shfl_down(mv, o, 64);
        if (tid == 0) atomicAdd(&accum[1], mv);
    }

    const float* aP = ctx + (size_t)(gm0 + wm * 16 + lr) * H_ + q * 8;
    const unsigned short* bB[5];
#pragma unroll
    for (int t = 0; t < 5; t++)
        bB[t] = WtG + (size_t)(wn * 80 + t * 16 + lr) * H_ + q * 8;

    floatx4 acc[5];
#pragma unroll
    for (int t = 0; t < 5; t++) acc[t] = (floatx4){0.f, 0.f, 0.f, 0.f};

    float4 a0[2], a1[2];
    short8 bv[2][5];
    // prologue: k-step 0
    a0[0] = *(const float4*)(aP + 0);
    a1[0] = *(const float4*)(aP + 4);
#pragma unroll
    for (int t = 0; t < 5; t++) bv[0][t] = *(const short8*)(bB[t] + 0);

#pragma unroll
    for (int i = 0; i < 32; i++) {
        const int cur = i & 1, nxt = cur ^ 1;
        if (i < 31) {
            const int k = (i + 1) * 32;
            a0[nxt] = *(const float4*)(aP + k);
            a1[nxt] = *(const float4*)(aP + k + 4);
#pragma unroll
            for (int t = 0; t < 5; t++) bv[nxt][t] = *(const short8*)(bB[t] + k);
        }
        short8 af;
        af[0] = (short)f2bf(a0[cur].x); af[1] = (short)f2bf(a0[cur].y);
        af[2] = (short)f2bf(a0[cur].z); af[3] = (short)f2bf(a0[cur].w);
        af[4] = (short)f2bf(a1[cur].x); af[5] = (short)f2bf(a1[cur].y);
        af[6] = (short)f2bf(a1[cur].z); af[7] = (short)f2bf(a1[cur].w);
#pragma unroll
        for (int t = 0; t < 5; t++)
            acc[t] = __builtin_amdgcn_mfma_f32_16x16x32_bf16(af, bv[cur][t], acc[t], 0, 0, 0);
    }

    // epilogue: logits -> BCE * mask -> sum
    float lsum = 0.0f;
#pragma unroll
    for (int t = 0; t < 5; t++) {
        const int col = wn * 80 + t * 16 + lr;
        if (col < NVALID) {
            const float rb = rowBias[b * NPAD + col];
#pragma unroll
            for (int i = 0; i < 4; i++) {
                const int row = gm0 + wm * 16 + q * 4 + i;
                const float l = acc[t][i] + rb;
                float tgt;
                if (col < 64)        tgt = oh[row * R_ + col];
                else if (col < 128)  tgt = ot[row * R_ + (col - 64)];
                else if (col == 128) tgt = ash[row];
                else                 tgt = ast[row];
                const float mk = masks[row];
                const float bce = fmaxf(l, 0.0f) - l * tgt + log1pf(__expf(-fabsf(l)));
                lsum += bce * mk;
            }
        }
    }
#pragma unroll
    for (int o = 32; o > 0; o >>= 1) lsum += __shfl_down(lsum, o, 64);
    if (lane == 0) rbuf[wave] = lsum;
    __syncthreads();
    if (tid == 0) atomicAdd(&accum[0], rbuf[0] + rbuf[1] + rbuf[2] + rbuf[3]);
}

// ---- K3: finalize ----
__global__ void finalize_kernel(const float* __restrict__ accum, float* __restrict__ out) {
    out[0] = accum[0] / accum[1];
}

extern "C" void kernel_launch(void* const* d_in, const int* in_sizes, int n_in,
                              void* d_out, int out_size, void* d_ws, size_t ws_size,
                              hipStream_t stream) {
    const float* ctx   = (const float*)d_in[0];
    const float* masks = (const float*)d_in[1];
    const float* ash   = (const float*)d_in[2];
    const float* ast   = (const float*)d_in[3];
    const float* sh    = (const float*)d_in[4];
    const float* st    = (const float*)d_in[5];
    const float* oh    = (const float*)d_in[6];
    const float* ot    = (const float*)d_in[7];
    const float* Ws_h  = (const float*)d_in[8];
    const float* Ws_t  = (const float*)d_in[10];
    const float* bs_h  = (const float*)d_in[9];
    const float* bs_t  = (const float*)d_in[11];
    const float* Wo_h  = (const float*)d_in[12];
    const float* bo_h  = (const float*)d_in[13];
    const float* Wo_t  = (const float*)d_in[14];
    const float* bo_t  = (const float*)d_in[15];
    float* out = (float*)d_out;

    char* ws = (char*)d_ws;
    float* accum   = (float*)(ws + 0);                 // [0]=loss sum, [1]=mask sum
    float* rowBias = (float*)(ws + 256);               // [32][160] fp32
    unsigned short* WtG = (unsigned short*)(ws + 256 + 32 * NPAD * 4); // [160][1024] bf16

    hipMemsetAsync(accum, 0, 8, stream);
    prep_kernel<<<NPAD + B_, 256, 0, stream>>>(ctx, sh, st, Ws_h, Ws_t,
                                               Wo_h, Wo_t, bo_h, bo_t, bs_h, bs_t,
                                               WtG, rowBias);
    main_kernel<<<M_ / 32, 256, 0, stream>>>(ctx, WtG, rowBias, masks,
                                             ash, ast, oh, ot, accum);
    finalize_kernel<<<1, 1, 0, stream>>>(accum, out);
}